// Round 5
// baseline (772.800 us; speedup 1.0000x reference)
//
#include <hip/hip_runtime.h>

#define D 64

// ---------------------------------------------------------------------------
// edge_index dtype detection (int32 vs int64), done per-block on device.
// int64 little-endian with values < 2^32 => every odd uint32 word is 0.
// int32 random indices in [0,100000): P(64 odd words all zero) ~ 1e-320.
// ---------------------------------------------------------------------------
#define DETECT_IS64(ei)                                        \
  __shared__ int s_is64;                                       \
  if (threadIdx.x == 0) {                                      \
    const unsigned int* w_ = (const unsigned int*)(ei);        \
    int is64_ = 1;                                             \
    for (int i_ = 0; i_ < 64; ++i_) {                          \
      if (w_[2 * i_ + 1] != 0u) { is64_ = 0; break; }          \
    }                                                          \
    s_is64 = is64_;                                            \
  }                                                            \
  __syncthreads();

// Grid/block for hist & place MUST be identical: shard = blockIdx & (S-1)
// must map each edge to the same shard in both kernels.
#define EDGE_GRID 4096
#define EDGE_BLOCK 256

// ---------------------------------------------------------------------------
// Kernel 1: sharded histogram. key = shard*N + dst, shard = blockIdx&(S-1).
// Cursor lines for shard s are only touched by blocks s mod S -> (with
// round-robin block->XCD dispatch) atomics stay XCD-local in L2.
// ---------------------------------------------------------------------------
__global__ __launch_bounds__(256) void gin_hist_sharded(
    const void* __restrict__ edge_index, int* __restrict__ C,
    int n_edges, int n_nodes, int nshard) {
  DETECT_IS64(edge_index);
  const int* ei32 = (const int*)edge_index;
  const long long* ei64 = (const long long*)edge_index;
  int* Cs = C + (size_t)(blockIdx.x & (nshard - 1)) * n_nodes;
  const int i = (int)(blockIdx.x * blockDim.x + threadIdx.x);
  const int stride = (int)(gridDim.x * blockDim.x);
  for (int e = i; e < n_edges; e += stride) {
    const int dst = s_is64 ? (int)ei64[n_edges + e] : ei32[n_edges + e];
    atomicAdd(&Cs[dst], 1);
  }
}

// ---------------------------------------------------------------------------
// Kernels 2a/2b/2c: in-place exclusive scan of C[total] (1024 chunks).
// ---------------------------------------------------------------------------
__global__ __launch_bounds__(256) void gin_scan_a(
    const int* __restrict__ C, int* __restrict__ tsum, int total, int chunk) {
  const int t = (int)(blockIdx.x * blockDim.x + threadIdx.x);
  if (t >= 1024) return;
  const int beg = t * chunk;
  const int end = min(beg + chunk, total);
  int s = 0;
  for (int i = beg; i < end; ++i) s += C[i];
  tsum[t] = s;
}

__global__ __launch_bounds__(1024) void gin_scan_b(int* __restrict__ tsum) {
  __shared__ int ls[1024];
  const int t = threadIdx.x;
  const int v = tsum[t];
  ls[t] = v;
  __syncthreads();
  for (int o = 1; o < 1024; o <<= 1) {
    const int a = (t >= o) ? ls[t - o] : 0;
    __syncthreads();
    ls[t] += a;
    __syncthreads();
  }
  tsum[t] = ls[t] - v;  // exclusive
}

__global__ __launch_bounds__(256) void gin_scan_c(
    int* __restrict__ C, const int* __restrict__ tsum, int total, int chunk) {
  const int t = (int)(blockIdx.x * blockDim.x + threadIdx.x);
  if (t >= 1024) return;
  const int beg = t * chunk;
  const int end = min(beg + chunk, total);
  int run = tsum[t];
  for (int i = beg; i < end; ++i) {
    const int c = C[i];
    C[i] = run;
    run += c;
  }
}

// ---------------------------------------------------------------------------
// Kernel 3: sharded placement. pos = atomicAdd(&C[shard*N+dst], 1).
// After this kernel, C[k] = exclusive_prefix[k+1], so the segment for key k
// is [C[k-1] (or 0 for k==0), C[k]). Shard regions of `sorted` are written
// by a single XCD -> L2 merges the 4B appends (write traffic ~6.4MB).
// ---------------------------------------------------------------------------
__global__ __launch_bounds__(256) void gin_place_sharded(
    const void* __restrict__ edge_index, int* __restrict__ C,
    int* __restrict__ sorted_src, int n_edges, int n_nodes, int nshard) {
  DETECT_IS64(edge_index);
  const int* ei32 = (const int*)edge_index;
  const long long* ei64 = (const long long*)edge_index;
  int* Cs = C + (size_t)(blockIdx.x & (nshard - 1)) * n_nodes;
  const int i = (int)(blockIdx.x * blockDim.x + threadIdx.x);
  const int stride = (int)(gridDim.x * blockDim.x);
  for (int e = i; e < n_edges; e += stride) {
    int src, dst;
    if (s_is64) {
      src = (int)ei64[e];
      dst = (int)ei64[n_edges + e];
    } else {
      src = ei32[e];
      dst = ei32[n_edges + e];
    }
    const int pos = atomicAdd(&Cs[dst], 1);
    sorted_src[pos] = src;
  }
}

// ---------------------------------------------------------------------------
// Kernel 4: gather-aggregate, wave per node, lane = feature.
// Walks the node's S per-shard segments in LOCKSTEP: up to S independent
// row-gathers in flight per iteration (memory-level parallelism against
// the L3-latency bound). All state statically indexed (fully unrolled).
// ---------------------------------------------------------------------------
template <int S>
__global__ __launch_bounds__(256) void gin_gather_sharded(
    const float* __restrict__ x, const int* __restrict__ C,
    const int* __restrict__ sorted_src, float* __restrict__ agg,
    int n_nodes) {
  const int lane = threadIdx.x & 63;
  const int wave = (int)((blockIdx.x * blockDim.x + threadIdx.x) >> 6);
  if (wave >= n_nodes) return;

  int p[S], q[S];
  float acc[S];
#pragma unroll
  for (int s = 0; s < S; ++s) {
    const int k = s * n_nodes + wave;
    q[s] = C[k];
    p[s] = (k == 0) ? 0 : C[k - 1];
    acc[s] = 0.0f;
  }

  bool more = true;
  while (more) {
    more = false;
#pragma unroll
    for (int s = 0; s < S; ++s) {
      if (p[s] < q[s]) {
        const int src = sorted_src[p[s]];
        p[s]++;
        acc[s] += x[(size_t)src * D + lane];
        more = more || (p[s] < q[s]);
      }
    }
  }

  float r = 0.0f;
#pragma unroll
  for (int s = 0; s < S; ++s) r += acc[s];
  agg[(size_t)wave * D + lane] = r;
}

// ---------------------------------------------------------------------------
// Fallback scatter (if ws too small): scalar float atomics, wave per edge.
// ---------------------------------------------------------------------------
__global__ __launch_bounds__(256) void gin_scatter_atomic(
    const float* __restrict__ x, const void* __restrict__ edge_index,
    float* __restrict__ agg, int n_edges) {
  DETECT_IS64(edge_index);
  const int* ei32 = (const int*)edge_index;
  const long long* ei64 = (const long long*)edge_index;
  const int lane = threadIdx.x & 63;
  int wave = (int)((blockIdx.x * blockDim.x + threadIdx.x) >> 6);
  const int nwaves = (int)((gridDim.x * blockDim.x) >> 6);
  for (int e = wave; e < n_edges; e += nwaves) {
    int src, dst;
    if (s_is64) {
      src = (int)ei64[e];
      dst = (int)ei64[n_edges + e];
    } else {
      src = ei32[e];
      dst = ei32[n_edges + e];
    }
    atomicAdd(&agg[(size_t)dst * D + lane], x[(size_t)src * D + lane]);
  }
}

// ---------------------------------------------------------------------------
// Fused per-node MLP, thread-per-node, register-resident (unchanged).
//   z = (1+eps)*x + agg ;  h = relu(W1 z + b1) ;  out = W2 h + b2
// ---------------------------------------------------------------------------
__global__ __launch_bounds__(256) void gin_mlp_kernel(
    const float* __restrict__ x,
    const float* __restrict__ agg_in,
    const float* __restrict__ eps_p,
    const float* __restrict__ W1, const float* __restrict__ b1,
    const float* __restrict__ W2, const float* __restrict__ b2,
    float* __restrict__ out,
    int n_nodes) {
  __shared__ float4 w1s[64 * 16];
  __shared__ float4 w2s[64 * 16];
  __shared__ float b1s[64];
  __shared__ float b2s[64];

  for (int t = threadIdx.x; t < 64 * 16; t += blockDim.x) {
    w1s[t] = ((const float4*)W1)[t];
    w2s[t] = ((const float4*)W2)[t];
  }
  if (threadIdx.x < 64) {
    b1s[threadIdx.x] = b1[threadIdx.x];
    b2s[threadIdx.x] = b2[threadIdx.x];
  }
  __syncthreads();

  const int n = (int)(blockIdx.x * blockDim.x + threadIdx.x);
  if (n >= n_nodes) return;

  const float scale = 1.0f + eps_p[0];
  const float4* xr = (const float4*)(x + (size_t)n * D);
  const float4* ar = (const float4*)(agg_in + (size_t)n * D);

  float4 z[16];
#pragma unroll
  for (int q = 0; q < 16; ++q) {
    const float4 xv = xr[q];
    const float4 av = ar[q];
    z[q].x = scale * xv.x + av.x;
    z[q].y = scale * xv.y + av.y;
    z[q].z = scale * xv.z + av.z;
    z[q].w = scale * xv.w + av.w;
  }

  float h[64];
#pragma unroll
  for (int j = 0; j < 64; ++j) {
    float acc = b1s[j];
#pragma unroll
    for (int q = 0; q < 16; ++q) {
      const float4 w = w1s[j * 16 + q];  // broadcast read
      acc += w.x * z[q].x + w.y * z[q].y + w.z * z[q].z + w.w * z[q].w;
    }
    h[j] = fmaxf(acc, 0.0f);
  }

  float4* orow = (float4*)(out + (size_t)n * D);
#pragma unroll
  for (int j4 = 0; j4 < 16; ++j4) {
    float4 o;
#pragma unroll
    for (int c = 0; c < 4; ++c) {
      const int j = 4 * j4 + c;
      float acc = b2s[j];
#pragma unroll
      for (int q = 0; q < 16; ++q) {
        const float4 w = w2s[j * 16 + q];  // broadcast read
        acc += w.x * h[4 * q + 0] + w.y * h[4 * q + 1] +
               w.z * h[4 * q + 2] + w.w * h[4 * q + 3];
      }
      ((float*)&o)[c] = acc;
    }
    orow[j4] = o;
  }
}

extern "C" void kernel_launch(void* const* d_in, const int* in_sizes, int n_in,
                              void* d_out, int out_size, void* d_ws, size_t ws_size,
                              hipStream_t stream) {
  const float* x   = (const float*)d_in[0];
  const void*  ei  = d_in[1];
  const float* eps = (const float*)d_in[2];
  const float* W1  = (const float*)d_in[3];
  const float* b1  = (const float*)d_in[4];
  const float* W2  = (const float*)d_in[5];
  const float* b2  = (const float*)d_in[6];
  float* out = (float*)d_out;

  const int n_nodes = in_sizes[0] / D;
  const int n_edges = in_sizes[1] / 2;

  // Pick the largest shard count the workspace supports.
  // ws layout (ints): C[S*n_nodes] | tsum[1024] | sorted[E]
  int S = 0;
  for (int cand = 8; cand >= 1; cand >>= 1) {
    const size_t need =
        ((size_t)cand * n_nodes + 1024 + (size_t)n_edges) * 4;
    if (ws_size >= need) { S = cand; break; }
  }

  if (S > 0) {
    int* C      = (int*)d_ws;
    int* tsum   = C + (size_t)S * n_nodes;
    int* sorted = tsum + 1024;
    const int total = S * n_nodes;

    (void)hipMemsetAsync(C, 0, (size_t)total * 4, stream);

    gin_hist_sharded<<<EDGE_GRID, EDGE_BLOCK, 0, stream>>>(ei, C, n_edges,
                                                           n_nodes, S);

    const int chunk = (total + 1023) / 1024;
    gin_scan_a<<<4, 256, 0, stream>>>(C, tsum, total, chunk);
    gin_scan_b<<<1, 1024, 0, stream>>>(tsum);
    gin_scan_c<<<4, 256, 0, stream>>>(C, tsum, total, chunk);

    gin_place_sharded<<<EDGE_GRID, EDGE_BLOCK, 0, stream>>>(ei, C, sorted,
                                                            n_edges, n_nodes,
                                                            S);

    const int gather_blocks = (n_nodes * 64 + 255) / 256;
    switch (S) {
      case 8:
        gin_gather_sharded<8><<<gather_blocks, 256, 0, stream>>>(
            x, C, sorted, out, n_nodes);
        break;
      case 4:
        gin_gather_sharded<4><<<gather_blocks, 256, 0, stream>>>(
            x, C, sorted, out, n_nodes);
        break;
      case 2:
        gin_gather_sharded<2><<<gather_blocks, 256, 0, stream>>>(
            x, C, sorted, out, n_nodes);
        break;
      default:
        gin_gather_sharded<1><<<gather_blocks, 256, 0, stream>>>(
            x, C, sorted, out, n_nodes);
        break;
    }
  } else {
    (void)hipMemsetAsync(out, 0, (size_t)n_nodes * D * sizeof(float), stream);
    gin_scatter_atomic<<<4096, 256, 0, stream>>>(x, ei, out, n_edges);
  }

  const int mlp_blocks = (n_nodes + 255) / 256;
  gin_mlp_kernel<<<mlp_blocks, 256, 0, stream>>>(x, out, eps, W1, b1, W2, b2,
                                                 out, n_nodes);
}

// Round 6
// 436.420 us; speedup vs baseline: 1.7708x; 1.7708x over previous
//
#include <hip/hip_runtime.h>

#define D 64

// ---------------------------------------------------------------------------
// edge_index dtype detection (int32 vs int64), done per-block on device.
// int64 little-endian with values < 2^32 => every odd uint32 word is 0.
// int32 random indices in [0,100000): P(64 odd words all zero) ~ 1e-320.
// ---------------------------------------------------------------------------
#define DETECT_IS64(ei)                                        \
  __shared__ int s_is64;                                       \
  if (threadIdx.x == 0) {                                      \
    const unsigned int* w_ = (const unsigned int*)(ei);        \
    int is64_ = 1;                                             \
    for (int i_ = 0; i_ < 64; ++i_) {                          \
      if (w_[2 * i_ + 1] != 0u) { is64_ = 0; break; }          \
    }                                                          \
    s_is64 = is64_;                                            \
  }                                                            \
  __syncthreads();

// Grid/block for hist & place MUST be identical: shard = blockIdx & (S-1)
// must map each edge to the same shard in both kernels.
#define EDGE_GRID 4096
#define EDGE_BLOCK 256

// Scan parallelism: 8192 chunks (round-5 lesson: 1024 x 782 serial iters
// was 335 us at 0.18% occupancy; 8192 x ~98 restores latency hiding).
#define SCAN_CHUNKS 8192

// ---------------------------------------------------------------------------
// Kernel 1: sharded histogram. key = shard*N + dst, shard = blockIdx&(S-1).
// Cursor lines for shard s are only touched by blocks with blockIdx%S == s
// -> (with round-robin block->XCD dispatch) atomics stay XCD-local in L2.
// ---------------------------------------------------------------------------
__global__ __launch_bounds__(256) void gin_hist_sharded(
    const void* __restrict__ edge_index, int* __restrict__ C,
    int n_edges, int n_nodes, int nshard) {
  DETECT_IS64(edge_index);
  const int* ei32 = (const int*)edge_index;
  const long long* ei64 = (const long long*)edge_index;
  int* Cs = C + (size_t)(blockIdx.x & (nshard - 1)) * n_nodes;
  const int i = (int)(blockIdx.x * blockDim.x + threadIdx.x);
  const int stride = (int)(gridDim.x * blockDim.x);
  for (int e = i; e < n_edges; e += stride) {
    const int dst = s_is64 ? (int)ei64[n_edges + e] : ei32[n_edges + e];
    atomicAdd(&Cs[dst], 1);
  }
}

// ---------------------------------------------------------------------------
// Kernels 2a/2b/2c: in-place exclusive scan of C[total], SCAN_CHUNKS chunks.
// ---------------------------------------------------------------------------
__global__ __launch_bounds__(256) void gin_scan_a(
    const int* __restrict__ C, int* __restrict__ tsum, int total, int chunk) {
  const int t = (int)(blockIdx.x * blockDim.x + threadIdx.x);
  if (t >= SCAN_CHUNKS) return;
  const int beg = t * chunk;
  const int end = min(beg + chunk, total);
  int s = 0;
  for (int i = beg; i < end; ++i) s += C[i];
  tsum[t] = s;
}

// One block, 1024 threads; each thread owns 8 contiguous partials.
__global__ __launch_bounds__(1024) void gin_scan_b(int* __restrict__ tsum) {
  __shared__ int ls[1024];
  const int t = threadIdx.x;
  int v[8];
  int s = 0;
#pragma unroll
  for (int i = 0; i < 8; ++i) {
    v[i] = tsum[t * 8 + i];
    s += v[i];
  }
  ls[t] = s;
  __syncthreads();
  for (int o = 1; o < 1024; o <<= 1) {
    const int a = (t >= o) ? ls[t - o] : 0;
    __syncthreads();
    ls[t] += a;
    __syncthreads();
  }
  int run = ls[t] - s;  // exclusive over this thread's 8
#pragma unroll
  for (int i = 0; i < 8; ++i) {
    tsum[t * 8 + i] = run;
    run += v[i];
  }
}

__global__ __launch_bounds__(256) void gin_scan_c(
    int* __restrict__ C, const int* __restrict__ tsum, int total, int chunk) {
  const int t = (int)(blockIdx.x * blockDim.x + threadIdx.x);
  if (t >= SCAN_CHUNKS) return;
  const int beg = t * chunk;
  const int end = min(beg + chunk, total);
  int run = tsum[t];
  for (int i = beg; i < end; ++i) {
    const int c = C[i];
    C[i] = run;
    run += c;
  }
}

// ---------------------------------------------------------------------------
// Kernel 3: sharded placement. pos = atomicAdd(&C[shard*N+dst], 1).
// After this kernel, C[k] = exclusive_prefix[k+1], so the segment for key k
// is [C[k-1] (or 0 for k==0), C[k]). Shard regions of `sorted` are written
// by a single XCD -> L2 merges the 4B appends.
// ---------------------------------------------------------------------------
__global__ __launch_bounds__(256) void gin_place_sharded(
    const void* __restrict__ edge_index, int* __restrict__ C,
    int* __restrict__ sorted_src, int n_edges, int n_nodes, int nshard) {
  DETECT_IS64(edge_index);
  const int* ei32 = (const int*)edge_index;
  const long long* ei64 = (const long long*)edge_index;
  int* Cs = C + (size_t)(blockIdx.x & (nshard - 1)) * n_nodes;
  const int i = (int)(blockIdx.x * blockDim.x + threadIdx.x);
  const int stride = (int)(gridDim.x * blockDim.x);
  for (int e = i; e < n_edges; e += stride) {
    int src, dst;
    if (s_is64) {
      src = (int)ei64[e];
      dst = (int)ei64[n_edges + e];
    } else {
      src = ei32[e];
      dst = ei32[n_edges + e];
    }
    const int pos = atomicAdd(&Cs[dst], 1);
    sorted_src[pos] = src;
  }
}

// ---------------------------------------------------------------------------
// Kernel 4: gather-aggregate, wave per node, lane = feature.
// Walks the node's S per-shard segments in LOCKSTEP: up to S independent
// row-gathers in flight per iteration (memory-level parallelism against
// the L3-latency bound). All state statically indexed (fully unrolled).
// ---------------------------------------------------------------------------
template <int S>
__global__ __launch_bounds__(256) void gin_gather_sharded(
    const float* __restrict__ x, const int* __restrict__ C,
    const int* __restrict__ sorted_src, float* __restrict__ agg,
    int n_nodes) {
  const int lane = threadIdx.x & 63;
  const int wave = (int)((blockIdx.x * blockDim.x + threadIdx.x) >> 6);
  if (wave >= n_nodes) return;

  int p[S], q[S];
  float acc[S];
#pragma unroll
  for (int s = 0; s < S; ++s) {
    const int k = s * n_nodes + wave;
    q[s] = C[k];
    p[s] = (k == 0) ? 0 : C[k - 1];
    acc[s] = 0.0f;
  }

  bool more = true;
  while (more) {
    more = false;
#pragma unroll
    for (int s = 0; s < S; ++s) {
      if (p[s] < q[s]) {
        const int src = sorted_src[p[s]];
        p[s]++;
        acc[s] += x[(size_t)src * D + lane];
        more = more || (p[s] < q[s]);
      }
    }
  }

  float r = 0.0f;
#pragma unroll
  for (int s = 0; s < S; ++s) r += acc[s];
  agg[(size_t)wave * D + lane] = r;
}

// ---------------------------------------------------------------------------
// Fallback scatter (if ws too small): scalar float atomics, wave per edge.
// ---------------------------------------------------------------------------
__global__ __launch_bounds__(256) void gin_scatter_atomic(
    const float* __restrict__ x, const void* __restrict__ edge_index,
    float* __restrict__ agg, int n_edges) {
  DETECT_IS64(edge_index);
  const int* ei32 = (const int*)edge_index;
  const long long* ei64 = (const long long*)edge_index;
  const int lane = threadIdx.x & 63;
  int wave = (int)((blockIdx.x * blockDim.x + threadIdx.x) >> 6);
  const int nwaves = (int)((gridDim.x * blockDim.x) >> 6);
  for (int e = wave; e < n_edges; e += nwaves) {
    int src, dst;
    if (s_is64) {
      src = (int)ei64[e];
      dst = (int)ei64[n_edges + e];
    } else {
      src = ei32[e];
      dst = ei32[n_edges + e];
    }
    atomicAdd(&agg[(size_t)dst * D + lane], x[(size_t)src * D + lane]);
  }
}

// ---------------------------------------------------------------------------
// Fused per-node MLP, thread-per-node, register-resident (unchanged).
//   z = (1+eps)*x + agg ;  h = relu(W1 z + b1) ;  out = W2 h + b2
// ---------------------------------------------------------------------------
__global__ __launch_bounds__(256) void gin_mlp_kernel(
    const float* __restrict__ x,
    const float* __restrict__ agg_in,
    const float* __restrict__ eps_p,
    const float* __restrict__ W1, const float* __restrict__ b1,
    const float* __restrict__ W2, const float* __restrict__ b2,
    float* __restrict__ out,
    int n_nodes) {
  __shared__ float4 w1s[64 * 16];
  __shared__ float4 w2s[64 * 16];
  __shared__ float b1s[64];
  __shared__ float b2s[64];

  for (int t = threadIdx.x; t < 64 * 16; t += blockDim.x) {
    w1s[t] = ((const float4*)W1)[t];
    w2s[t] = ((const float4*)W2)[t];
  }
  if (threadIdx.x < 64) {
    b1s[threadIdx.x] = b1[threadIdx.x];
    b2s[threadIdx.x] = b2[threadIdx.x];
  }
  __syncthreads();

  const int n = (int)(blockIdx.x * blockDim.x + threadIdx.x);
  if (n >= n_nodes) return;

  const float scale = 1.0f + eps_p[0];
  const float4* xr = (const float4*)(x + (size_t)n * D);
  const float4* ar = (const float4*)(agg_in + (size_t)n * D);

  float4 z[16];
#pragma unroll
  for (int q = 0; q < 16; ++q) {
    const float4 xv = xr[q];
    const float4 av = ar[q];
    z[q].x = scale * xv.x + av.x;
    z[q].y = scale * xv.y + av.y;
    z[q].z = scale * xv.z + av.z;
    z[q].w = scale * xv.w + av.w;
  }

  float h[64];
#pragma unroll
  for (int j = 0; j < 64; ++j) {
    float acc = b1s[j];
#pragma unroll
    for (int q = 0; q < 16; ++q) {
      const float4 w = w1s[j * 16 + q];  // broadcast read
      acc += w.x * z[q].x + w.y * z[q].y + w.z * z[q].z + w.w * z[q].w;
    }
    h[j] = fmaxf(acc, 0.0f);
  }

  float4* orow = (float4*)(out + (size_t)n * D);
#pragma unroll
  for (int j4 = 0; j4 < 16; ++j4) {
    float4 o;
#pragma unroll
    for (int c = 0; c < 4; ++c) {
      const int j = 4 * j4 + c;
      float acc = b2s[j];
#pragma unroll
      for (int q = 0; q < 16; ++q) {
        const float4 w = w2s[j * 16 + q];  // broadcast read
        acc += w.x * h[4 * q + 0] + w.y * h[4 * q + 1] +
               w.z * h[4 * q + 2] + w.w * h[4 * q + 3];
      }
      ((float*)&o)[c] = acc;
    }
    orow[j4] = o;
  }
}

extern "C" void kernel_launch(void* const* d_in, const int* in_sizes, int n_in,
                              void* d_out, int out_size, void* d_ws, size_t ws_size,
                              hipStream_t stream) {
  const float* x   = (const float*)d_in[0];
  const void*  ei  = d_in[1];
  const float* eps = (const float*)d_in[2];
  const float* W1  = (const float*)d_in[3];
  const float* b1  = (const float*)d_in[4];
  const float* W2  = (const float*)d_in[5];
  const float* b2  = (const float*)d_in[6];
  float* out = (float*)d_out;

  const int n_nodes = in_sizes[0] / D;
  const int n_edges = in_sizes[1] / 2;

  // Pick the largest shard count the workspace supports.
  // ws layout (ints): C[S*n_nodes] | tsum[SCAN_CHUNKS] | sorted[E]
  int S = 0;
  for (int cand = 8; cand >= 1; cand >>= 1) {
    const size_t need =
        ((size_t)cand * n_nodes + SCAN_CHUNKS + (size_t)n_edges) * 4;
    if (ws_size >= need) { S = cand; break; }
  }

  if (S > 0) {
    int* C      = (int*)d_ws;
    int* tsum   = C + (size_t)S * n_nodes;
    int* sorted = tsum + SCAN_CHUNKS;
    const int total = S * n_nodes;

    (void)hipMemsetAsync(C, 0, (size_t)total * 4, stream);

    gin_hist_sharded<<<EDGE_GRID, EDGE_BLOCK, 0, stream>>>(ei, C, n_edges,
                                                           n_nodes, S);

    const int chunk = (total + SCAN_CHUNKS - 1) / SCAN_CHUNKS;
    gin_scan_a<<<SCAN_CHUNKS / 256, 256, 0, stream>>>(C, tsum, total, chunk);
    gin_scan_b<<<1, 1024, 0, stream>>>(tsum);
    gin_scan_c<<<SCAN_CHUNKS / 256, 256, 0, stream>>>(C, tsum, total, chunk);

    gin_place_sharded<<<EDGE_GRID, EDGE_BLOCK, 0, stream>>>(ei, C, sorted,
                                                            n_edges, n_nodes,
                                                            S);

    const int gather_blocks = (n_nodes * 64 + 255) / 256;
    switch (S) {
      case 8:
        gin_gather_sharded<8><<<gather_blocks, 256, 0, stream>>>(
            x, C, sorted, out, n_nodes);
        break;
      case 4:
        gin_gather_sharded<4><<<gather_blocks, 256, 0, stream>>>(
            x, C, sorted, out, n_nodes);
        break;
      case 2:
        gin_gather_sharded<2><<<gather_blocks, 256, 0, stream>>>(
            x, C, sorted, out, n_nodes);
        break;
      default:
        gin_gather_sharded<1><<<gather_blocks, 256, 0, stream>>>(
            x, C, sorted, out, n_nodes);
        break;
    }
  } else {
    (void)hipMemsetAsync(out, 0, (size_t)n_nodes * D * sizeof(float), stream);
    gin_scatter_atomic<<<4096, 256, 0, stream>>>(x, ei, out, n_edges);
  }

  const int mlp_blocks = (n_nodes + 255) / 256;
  gin_mlp_kernel<<<mlp_blocks, 256, 0, stream>>>(x, out, eps, W1, b1, W2, b2,
                                                 out, n_nodes);
}

// Round 7
// 397.311 us; speedup vs baseline: 1.9451x; 1.0984x over previous
//
#include <hip/hip_runtime.h>

#define D 64

// ---------------------------------------------------------------------------
// edge_index dtype detection (int32 vs int64), done per-block on device.
// int64 little-endian with values < 2^32 => every odd uint32 word is 0.
// int32 random indices in [0,100000): P(64 odd words all zero) ~ 1e-320.
// ---------------------------------------------------------------------------
#define DETECT_IS64(ei)                                        \
  __shared__ int s_is64;                                       \
  if (threadIdx.x == 0) {                                      \
    const unsigned int* w_ = (const unsigned int*)(ei);        \
    int is64_ = 1;                                             \
    for (int i_ = 0; i_ < 64; ++i_) {                          \
      if (w_[2 * i_ + 1] != 0u) { is64_ = 0; break; }          \
    }                                                          \
    s_is64 = is64_;                                            \
  }                                                            \
  __syncthreads();

// Grid/block for hist & place MUST be identical: shard = blockIdx & (S-1)
// must map each edge to the same shard in both kernels.
#define EDGE_GRID 4096
#define EDGE_BLOCK 256

// Scan parallelism: 8192 chunks (round-5 lesson: 1024 x 782 serial iters
// was 335 us at 0.18% occupancy; 8192 x ~98 restores latency hiding).
#define SCAN_CHUNKS 8192

// ---------------------------------------------------------------------------
// Kernel 1: sharded histogram. key = shard*N + dst, shard = blockIdx&(S-1).
// Cursor lines for shard s are only touched by blocks with blockIdx%S == s
// -> (with round-robin block->XCD dispatch) atomics stay XCD-local in L2.
// ---------------------------------------------------------------------------
__global__ __launch_bounds__(256) void gin_hist_sharded(
    const void* __restrict__ edge_index, int* __restrict__ C,
    int n_edges, int n_nodes, int nshard) {
  DETECT_IS64(edge_index);
  const int* ei32 = (const int*)edge_index;
  const long long* ei64 = (const long long*)edge_index;
  int* Cs = C + (size_t)(blockIdx.x & (nshard - 1)) * n_nodes;
  const int i = (int)(blockIdx.x * blockDim.x + threadIdx.x);
  const int stride = (int)(gridDim.x * blockDim.x);
  for (int e = i; e < n_edges; e += stride) {
    const int dst = s_is64 ? (int)ei64[n_edges + e] : ei32[n_edges + e];
    atomicAdd(&Cs[dst], 1);
  }
}

// ---------------------------------------------------------------------------
// Kernels 2a/2b/2c: in-place exclusive scan of C[total], SCAN_CHUNKS chunks.
// ---------------------------------------------------------------------------
__global__ __launch_bounds__(256) void gin_scan_a(
    const int* __restrict__ C, int* __restrict__ tsum, int total, int chunk) {
  const int t = (int)(blockIdx.x * blockDim.x + threadIdx.x);
  if (t >= SCAN_CHUNKS) return;
  const int beg = t * chunk;
  const int end = min(beg + chunk, total);
  int s = 0;
  for (int i = beg; i < end; ++i) s += C[i];
  tsum[t] = s;
}

// One block, 1024 threads; each thread owns 8 contiguous partials.
__global__ __launch_bounds__(1024) void gin_scan_b(int* __restrict__ tsum) {
  __shared__ int ls[1024];
  const int t = threadIdx.x;
  int v[8];
  int s = 0;
#pragma unroll
  for (int i = 0; i < 8; ++i) {
    v[i] = tsum[t * 8 + i];
    s += v[i];
  }
  ls[t] = s;
  __syncthreads();
  for (int o = 1; o < 1024; o <<= 1) {
    const int a = (t >= o) ? ls[t - o] : 0;
    __syncthreads();
    ls[t] += a;
    __syncthreads();
  }
  int run = ls[t] - s;  // exclusive over this thread's 8
#pragma unroll
  for (int i = 0; i < 8; ++i) {
    tsum[t * 8 + i] = run;
    run += v[i];
  }
}

__global__ __launch_bounds__(256) void gin_scan_c(
    int* __restrict__ C, const int* __restrict__ tsum, int total, int chunk) {
  const int t = (int)(blockIdx.x * blockDim.x + threadIdx.x);
  if (t >= SCAN_CHUNKS) return;
  const int beg = t * chunk;
  const int end = min(beg + chunk, total);
  int run = tsum[t];
  for (int i = beg; i < end; ++i) {
    const int c = C[i];
    C[i] = run;
    run += c;
  }
}

// ---------------------------------------------------------------------------
// Kernel 3: sharded placement. pos = atomicAdd(&C[shard*N+dst], 1).
// After this kernel, C[k] = exclusive_prefix[k+1], so the segment for key k
// is [C[k-1] (or 0 for k==0), C[k]). Shard regions of `sorted` are written
// by a single XCD -> L2 merges the 4B appends.
// ---------------------------------------------------------------------------
__global__ __launch_bounds__(256) void gin_place_sharded(
    const void* __restrict__ edge_index, int* __restrict__ C,
    int* __restrict__ sorted_src, int n_edges, int n_nodes, int nshard) {
  DETECT_IS64(edge_index);
  const int* ei32 = (const int*)edge_index;
  const long long* ei64 = (const long long*)edge_index;
  int* Cs = C + (size_t)(blockIdx.x & (nshard - 1)) * n_nodes;
  const int i = (int)(blockIdx.x * blockDim.x + threadIdx.x);
  const int stride = (int)(gridDim.x * blockDim.x);
  for (int e = i; e < n_edges; e += stride) {
    int src, dst;
    if (s_is64) {
      src = (int)ei64[e];
      dst = (int)ei64[n_edges + e];
    } else {
      src = ei32[e];
      dst = ei32[n_edges + e];
    }
    const int pos = atomicAdd(&Cs[dst], 1);
    sorted_src[pos] = src;
  }
}

// ---------------------------------------------------------------------------
// Kernel 4: gather-aggregate, wave per node, lane = feature.
// BRANCHLESS lockstep over the node's S per-shard segments: all S index
// loads and all S row loads issue unconditionally every iteration (inactive
// streams use a clamped-safe index 0 -> L1 hit), accumulate predicated.
// Round-6 lesson: `if (p<q)` around the loads serialized them; this version
// gives the memory system S independent row-gathers per latency hop.
// ---------------------------------------------------------------------------
template <int S>
__global__ __launch_bounds__(256) void gin_gather_sharded(
    const float* __restrict__ x, const int* __restrict__ C,
    const int* __restrict__ sorted_src, float* __restrict__ agg,
    int n_nodes) {
  const int lane = threadIdx.x & 63;
  const int wave = (int)((blockIdx.x * blockDim.x + threadIdx.x) >> 6);
  if (wave >= n_nodes) return;

  int p[S], q[S];
  float acc[S];
  bool more = false;
#pragma unroll
  for (int s = 0; s < S; ++s) {
    const int k = s * n_nodes + wave;
    q[s] = C[k];
    p[s] = (k == 0) ? 0 : C[k - 1];
    acc[s] = 0.0f;
    more = more || (p[s] < q[s]);
  }

  while (more) {
    int act[S], srcs[S];
#pragma unroll
    for (int s = 0; s < S; ++s) {
      act[s] = (p[s] < q[s]) ? 1 : 0;
      srcs[s] = sorted_src[act[s] ? p[s] : 0];  // unconditional load
    }
    float rows[S];
#pragma unroll
    for (int s = 0; s < S; ++s) {
      rows[s] = x[(size_t)srcs[s] * D + lane];  // unconditional load
    }
    more = false;
#pragma unroll
    for (int s = 0; s < S; ++s) {
      acc[s] += act[s] ? rows[s] : 0.0f;
      p[s] += act[s];
      more = more || (p[s] < q[s]);
    }
  }

  float r = 0.0f;
#pragma unroll
  for (int s = 0; s < S; ++s) r += acc[s];
  agg[(size_t)wave * D + lane] = r;
}

// ---------------------------------------------------------------------------
// Fallback scatter (if ws too small): scalar float atomics, wave per edge.
// ---------------------------------------------------------------------------
__global__ __launch_bounds__(256) void gin_scatter_atomic(
    const float* __restrict__ x, const void* __restrict__ edge_index,
    float* __restrict__ agg, int n_edges) {
  DETECT_IS64(edge_index);
  const int* ei32 = (const int*)edge_index;
  const long long* ei64 = (const long long*)edge_index;
  const int lane = threadIdx.x & 63;
  int wave = (int)((blockIdx.x * blockDim.x + threadIdx.x) >> 6);
  const int nwaves = (int)((gridDim.x * blockDim.x) >> 6);
  for (int e = wave; e < n_edges; e += nwaves) {
    int src, dst;
    if (s_is64) {
      src = (int)ei64[e];
      dst = (int)ei64[n_edges + e];
    } else {
      src = ei32[e];
      dst = ei32[n_edges + e];
    }
    atomicAdd(&agg[(size_t)dst * D + lane], x[(size_t)src * D + lane]);
  }
}

// ---------------------------------------------------------------------------
// Fused per-node MLP, thread-per-node, NO LDS.
//   z = (1+eps)*x + agg ;  h = relu(W1 z + b1) ;  out = W2 h + b2
// Weight addresses depend only on compile-time loop indices -> the AMDGPU
// uniformity analysis scalarizes them (s_load_dwordx4 + SGPR-operand FMAs).
// Round-6 lesson: the LDS-broadcast version issued 2048 ds_read_b128 per
// thread (205M total) = LDS-pipe bound ~150us; FLOP floor is ~10us.
// Both layers fully unrolled so z[]/h[] stay statically indexed in VGPRs.
// agg_in may alias out (each thread reads only its own row before writing).
// ---------------------------------------------------------------------------
__global__ __launch_bounds__(256) void gin_mlp_kernel(
    const float* __restrict__ x,
    const float* __restrict__ agg_in,
    const float* __restrict__ eps_p,
    const float* __restrict__ W1, const float* __restrict__ b1,
    const float* __restrict__ W2, const float* __restrict__ b2,
    float* __restrict__ out,
    int n_nodes) {
  const int n = (int)(blockIdx.x * blockDim.x + threadIdx.x);
  if (n >= n_nodes) return;

  const float scale = 1.0f + eps_p[0];
  const float4* xr = (const float4*)(x + (size_t)n * D);
  const float4* ar = (const float4*)(agg_in + (size_t)n * D);
  const float4* W1v = (const float4*)W1;
  const float4* W2v = (const float4*)W2;

  float4 z[16];
#pragma unroll
  for (int q = 0; q < 16; ++q) {
    const float4 xv = xr[q];
    const float4 av = ar[q];
    z[q].x = scale * xv.x + av.x;
    z[q].y = scale * xv.y + av.y;
    z[q].z = scale * xv.z + av.z;
    z[q].w = scale * xv.w + av.w;
  }

  float h[64];
#pragma unroll
  for (int j = 0; j < 64; ++j) {
    float acc = b1[j];  // uniform -> s_load
#pragma unroll
    for (int q = 0; q < 16; ++q) {
      const float4 w = W1v[j * 16 + q];  // uniform -> s_load_dwordx4
      acc += w.x * z[q].x + w.y * z[q].y + w.z * z[q].z + w.w * z[q].w;
    }
    h[j] = fmaxf(acc, 0.0f);
  }

  float4* orow = (float4*)(out + (size_t)n * D);
#pragma unroll
  for (int j4 = 0; j4 < 16; ++j4) {
    float4 o;
#pragma unroll
    for (int c = 0; c < 4; ++c) {
      const int j = 4 * j4 + c;
      float acc = b2[j];  // uniform -> s_load
#pragma unroll
      for (int q = 0; q < 16; ++q) {
        const float4 w = W2v[j * 16 + q];  // uniform -> s_load_dwordx4
        acc += w.x * h[4 * q + 0] + w.y * h[4 * q + 1] +
               w.z * h[4 * q + 2] + w.w * h[4 * q + 3];
      }
      ((float*)&o)[c] = acc;
    }
    orow[j4] = o;
  }
}

extern "C" void kernel_launch(void* const* d_in, const int* in_sizes, int n_in,
                              void* d_out, int out_size, void* d_ws, size_t ws_size,
                              hipStream_t stream) {
  const float* x   = (const float*)d_in[0];
  const void*  ei  = d_in[1];
  const float* eps = (const float*)d_in[2];
  const float* W1  = (const float*)d_in[3];
  const float* b1  = (const float*)d_in[4];
  const float* W2  = (const float*)d_in[5];
  const float* b2  = (const float*)d_in[6];
  float* out = (float*)d_out;

  const int n_nodes = in_sizes[0] / D;
  const int n_edges = in_sizes[1] / 2;

  // Pick the largest shard count the workspace supports.
  // ws layout (ints): C[S*n_nodes] | tsum[SCAN_CHUNKS] | sorted[E]
  int S = 0;
  for (int cand = 8; cand >= 1; cand >>= 1) {
    const size_t need =
        ((size_t)cand * n_nodes + SCAN_CHUNKS + (size_t)n_edges) * 4;
    if (ws_size >= need) { S = cand; break; }
  }

  if (S > 0) {
    int* C      = (int*)d_ws;
    int* tsum   = C + (size_t)S * n_nodes;
    int* sorted = tsum + SCAN_CHUNKS;
    const int total = S * n_nodes;

    (void)hipMemsetAsync(C, 0, (size_t)total * 4, stream);

    gin_hist_sharded<<<EDGE_GRID, EDGE_BLOCK, 0, stream>>>(ei, C, n_edges,
                                                           n_nodes, S);

    const int chunk = (total + SCAN_CHUNKS - 1) / SCAN_CHUNKS;
    gin_scan_a<<<SCAN_CHUNKS / 256, 256, 0, stream>>>(C, tsum, total, chunk);
    gin_scan_b<<<1, 1024, 0, stream>>>(tsum);
    gin_scan_c<<<SCAN_CHUNKS / 256, 256, 0, stream>>>(C, tsum, total, chunk);

    gin_place_sharded<<<EDGE_GRID, EDGE_BLOCK, 0, stream>>>(ei, C, sorted,
                                                            n_edges, n_nodes,
                                                            S);

    const int gather_blocks = (n_nodes * 64 + 255) / 256;
    switch (S) {
      case 8:
        gin_gather_sharded<8><<<gather_blocks, 256, 0, stream>>>(
            x, C, sorted, out, n_nodes);
        break;
      case 4:
        gin_gather_sharded<4><<<gather_blocks, 256, 0, stream>>>(
            x, C, sorted, out, n_nodes);
        break;
      case 2:
        gin_gather_sharded<2><<<gather_blocks, 256, 0, stream>>>(
            x, C, sorted, out, n_nodes);
        break;
      default:
        gin_gather_sharded<1><<<gather_blocks, 256, 0, stream>>>(
            x, C, sorted, out, n_nodes);
        break;
    }
  } else {
    (void)hipMemsetAsync(out, 0, (size_t)n_nodes * D * sizeof(float), stream);
    gin_scatter_atomic<<<4096, 256, 0, stream>>>(x, ei, out, n_edges);
  }

  const int mlp_blocks = (n_nodes + 255) / 256;
  gin_mlp_kernel<<<mlp_blocks, 256, 0, stream>>>(x, out, eps, W1, b1, W2, b2,
                                                 out, n_nodes);
}

// Round 8
// 393.271 us; speedup vs baseline: 1.9651x; 1.0103x over previous
//
#include <hip/hip_runtime.h>

#define D 64

// ---------------------------------------------------------------------------
// edge_index dtype detection (int32 vs int64), done per-block on device.
// int64 little-endian with values < 2^32 => every odd uint32 word is 0.
// int32 random indices in [0,100000): P(64 odd words all zero) ~ 1e-320.
// ---------------------------------------------------------------------------
#define DETECT_IS64(ei)                                        \
  __shared__ int s_is64;                                       \
  if (threadIdx.x == 0) {                                      \
    const unsigned int* w_ = (const unsigned int*)(ei);        \
    int is64_ = 1;                                             \
    for (int i_ = 0; i_ < 64; ++i_) {                          \
      if (w_[2 * i_ + 1] != 0u) { is64_ = 0; break; }          \
    }                                                          \
    s_is64 = is64_;                                            \
  }                                                            \
  __syncthreads();

// Grid/block for hist & place MUST be identical: shard = blockIdx & (S-1)
// must map each edge to the same shard in both kernels.
#define EDGE_GRID 4096
#define EDGE_BLOCK 256

// Scan parallelism: 8192 chunks (round-5 lesson: 1024 x 782 serial iters
// was 335 us at 0.18% occupancy; 8192 x ~98 restores latency hiding).
#define SCAN_CHUNKS 8192

// ---------------------------------------------------------------------------
// Kernel 1: sharded histogram. key = shard*N + dst, shard = blockIdx&(S-1).
// Cursor lines for shard s are only touched by blocks with blockIdx%S == s
// -> (with round-robin block->XCD dispatch) atomics stay XCD-local in L2.
// ---------------------------------------------------------------------------
__global__ __launch_bounds__(256) void gin_hist_sharded(
    const void* __restrict__ edge_index, int* __restrict__ C,
    int n_edges, int n_nodes, int nshard) {
  DETECT_IS64(edge_index);
  const int* ei32 = (const int*)edge_index;
  const long long* ei64 = (const long long*)edge_index;
  int* Cs = C + (size_t)(blockIdx.x & (nshard - 1)) * n_nodes;
  const int i = (int)(blockIdx.x * blockDim.x + threadIdx.x);
  const int stride = (int)(gridDim.x * blockDim.x);
  for (int e = i; e < n_edges; e += stride) {
    const int dst = s_is64 ? (int)ei64[n_edges + e] : ei32[n_edges + e];
    atomicAdd(&Cs[dst], 1);
  }
}

// ---------------------------------------------------------------------------
// Kernels 2a/2b/2c: in-place exclusive scan of C[total], SCAN_CHUNKS chunks.
// ---------------------------------------------------------------------------
__global__ __launch_bounds__(256) void gin_scan_a(
    const int* __restrict__ C, int* __restrict__ tsum, int total, int chunk) {
  const int t = (int)(blockIdx.x * blockDim.x + threadIdx.x);
  if (t >= SCAN_CHUNKS) return;
  const int beg = t * chunk;
  const int end = min(beg + chunk, total);
  int s = 0;
  for (int i = beg; i < end; ++i) s += C[i];
  tsum[t] = s;
}

// One block, 1024 threads; each thread owns 8 contiguous partials.
__global__ __launch_bounds__(1024) void gin_scan_b(int* __restrict__ tsum) {
  __shared__ int ls[1024];
  const int t = threadIdx.x;
  int v[8];
  int s = 0;
#pragma unroll
  for (int i = 0; i < 8; ++i) {
    v[i] = tsum[t * 8 + i];
    s += v[i];
  }
  ls[t] = s;
  __syncthreads();
  for (int o = 1; o < 1024; o <<= 1) {
    const int a = (t >= o) ? ls[t - o] : 0;
    __syncthreads();
    ls[t] += a;
    __syncthreads();
  }
  int run = ls[t] - s;  // exclusive over this thread's 8
#pragma unroll
  for (int i = 0; i < 8; ++i) {
    tsum[t * 8 + i] = run;
    run += v[i];
  }
}

__global__ __launch_bounds__(256) void gin_scan_c(
    int* __restrict__ C, const int* __restrict__ tsum, int total, int chunk) {
  const int t = (int)(blockIdx.x * blockDim.x + threadIdx.x);
  if (t >= SCAN_CHUNKS) return;
  const int beg = t * chunk;
  const int end = min(beg + chunk, total);
  int run = tsum[t];
  for (int i = beg; i < end; ++i) {
    const int c = C[i];
    C[i] = run;
    run += c;
  }
}

// ---------------------------------------------------------------------------
// Kernel 3: sharded placement. pos = atomicAdd(&C[shard*N+dst], 1).
// After this kernel, C[k] = exclusive_prefix[k+1], so the segment for key k
// is [C[k-1] (or 0 for k==0), C[k]). Shard regions of `sorted` are written
// by a single XCD -> L2 merges the 4B appends.
// ---------------------------------------------------------------------------
__global__ __launch_bounds__(256) void gin_place_sharded(
    const void* __restrict__ edge_index, int* __restrict__ C,
    int* __restrict__ sorted_src, int n_edges, int n_nodes, int nshard) {
  DETECT_IS64(edge_index);
  const int* ei32 = (const int*)edge_index;
  const long long* ei64 = (const long long*)edge_index;
  int* Cs = C + (size_t)(blockIdx.x & (nshard - 1)) * n_nodes;
  const int i = (int)(blockIdx.x * blockDim.x + threadIdx.x);
  const int stride = (int)(gridDim.x * blockDim.x);
  for (int e = i; e < n_edges; e += stride) {
    int src, dst;
    if (s_is64) {
      src = (int)ei64[e];
      dst = (int)ei64[n_edges + e];
    } else {
      src = ei32[e];
      dst = ei32[n_edges + e];
    }
    const int pos = atomicAdd(&Cs[dst], 1);
    sorted_src[pos] = src;
  }
}

// ---------------------------------------------------------------------------
// Kernel 4: gather-aggregate, wave per node, lane = feature.
// BRANCHLESS lockstep over the node's S per-shard segments: all S index
// loads and all S row loads issue unconditionally every iteration (inactive
// streams use a clamped-safe index 0 -> L1 hit), accumulate predicated.
// Round-6 lesson: `if (p<q)` around the loads serialized them; this version
// gives the memory system S independent row-gathers per latency hop.
// ---------------------------------------------------------------------------
template <int S>
__global__ __launch_bounds__(256) void gin_gather_sharded(
    const float* __restrict__ x, const int* __restrict__ C,
    const int* __restrict__ sorted_src, float* __restrict__ agg,
    int n_nodes) {
  const int lane = threadIdx.x & 63;
  const int wave = (int)((blockIdx.x * blockDim.x + threadIdx.x) >> 6);
  if (wave >= n_nodes) return;

  int p[S], q[S];
  float acc[S];
  bool more = false;
#pragma unroll
  for (int s = 0; s < S; ++s) {
    const int k = s * n_nodes + wave;
    q[s] = C[k];
    p[s] = (k == 0) ? 0 : C[k - 1];
    acc[s] = 0.0f;
    more = more || (p[s] < q[s]);
  }

  while (more) {
    int act[S], srcs[S];
#pragma unroll
    for (int s = 0; s < S; ++s) {
      act[s] = (p[s] < q[s]) ? 1 : 0;
      srcs[s] = sorted_src[act[s] ? p[s] : 0];  // unconditional load
    }
    float rows[S];
#pragma unroll
    for (int s = 0; s < S; ++s) {
      rows[s] = x[(size_t)srcs[s] * D + lane];  // unconditional load
    }
    more = false;
#pragma unroll
    for (int s = 0; s < S; ++s) {
      acc[s] += act[s] ? rows[s] : 0.0f;
      p[s] += act[s];
      more = more || (p[s] < q[s]);
    }
  }

  float r = 0.0f;
#pragma unroll
  for (int s = 0; s < S; ++s) r += acc[s];
  agg[(size_t)wave * D + lane] = r;
}

// ---------------------------------------------------------------------------
// Fallback scatter (if ws too small): scalar float atomics, wave per edge.
// ---------------------------------------------------------------------------
__global__ __launch_bounds__(256) void gin_scatter_atomic(
    const float* __restrict__ x, const void* __restrict__ edge_index,
    float* __restrict__ agg, int n_edges) {
  DETECT_IS64(edge_index);
  const int* ei32 = (const int*)edge_index;
  const long long* ei64 = (const long long*)edge_index;
  const int lane = threadIdx.x & 63;
  int wave = (int)((blockIdx.x * blockDim.x + threadIdx.x) >> 6);
  const int nwaves = (int)((gridDim.x * blockDim.x) >> 6);
  for (int e = wave; e < n_edges; e += nwaves) {
    int src, dst;
    if (s_is64) {
      src = (int)ei64[e];
      dst = (int)ei64[n_edges + e];
    } else {
      src = ei32[e];
      dst = ei32[n_edges + e];
    }
    atomicAdd(&agg[(size_t)dst * D + lane], x[(size_t)src * D + lane]);
  }
}

// ---------------------------------------------------------------------------
// Fused per-node MLP, thread-per-node, NO LDS.
//   z = (1+eps)*x + agg ;  h = relu(W1 z + b1) ;  out = W2 h + b2
// Weight addresses depend only on compile-time loop indices -> the AMDGPU
// uniformity analysis scalarizes them (s_load_dwordx4 + SGPR-operand FMAs).
// Round-6 lesson: the LDS-broadcast version issued 2048 ds_read_b128 per
// thread (205M total) = LDS-pipe bound ~150us; FLOP floor is ~10us.
// Both layers fully unrolled so z[]/h[] stay statically indexed in VGPRs.
// agg_in may alias out (each thread reads only its own row before writing).
// ---------------------------------------------------------------------------
__global__ __launch_bounds__(256) void gin_mlp_kernel(
    const float* __restrict__ x,
    const float* __restrict__ agg_in,
    const float* __restrict__ eps_p,
    const float* __restrict__ W1, const float* __restrict__ b1,
    const float* __restrict__ W2, const float* __restrict__ b2,
    float* __restrict__ out,
    int n_nodes) {
  const int n = (int)(blockIdx.x * blockDim.x + threadIdx.x);
  if (n >= n_nodes) return;

  const float scale = 1.0f + eps_p[0];
  const float4* xr = (const float4*)(x + (size_t)n * D);
  const float4* ar = (const float4*)(agg_in + (size_t)n * D);
  const float4* W1v = (const float4*)W1;
  const float4* W2v = (const float4*)W2;

  float4 z[16];
#pragma unroll
  for (int q = 0; q < 16; ++q) {
    const float4 xv = xr[q];
    const float4 av = ar[q];
    z[q].x = scale * xv.x + av.x;
    z[q].y = scale * xv.y + av.y;
    z[q].z = scale * xv.z + av.z;
    z[q].w = scale * xv.w + av.w;
  }

  float h[64];
#pragma unroll
  for (int j = 0; j < 64; ++j) {
    float acc = b1[j];  // uniform -> s_load
#pragma unroll
    for (int q = 0; q < 16; ++q) {
      const float4 w = W1v[j * 16 + q];  // uniform -> s_load_dwordx4
      acc += w.x * z[q].x + w.y * z[q].y + w.z * z[q].z + w.w * z[q].w;
    }
    h[j] = fmaxf(acc, 0.0f);
  }

  float4* orow = (float4*)(out + (size_t)n * D);
#pragma unroll
  for (int j4 = 0; j4 < 16; ++j4) {
    float4 o;
#pragma unroll
    for (int c = 0; c < 4; ++c) {
      const int j = 4 * j4 + c;
      float acc = b2[j];  // uniform -> s_load
#pragma unroll
      for (int q = 0; q < 16; ++q) {
        const float4 w = W2v[j * 16 + q];  // uniform -> s_load_dwordx4
        acc += w.x * h[4 * q + 0] + w.y * h[4 * q + 1] +
               w.z * h[4 * q + 2] + w.w * h[4 * q + 3];
      }
      ((float*)&o)[c] = acc;
    }
    orow[j4] = o;
  }
}

extern "C" void kernel_launch(void* const* d_in, const int* in_sizes, int n_in,
                              void* d_out, int out_size, void* d_ws, size_t ws_size,
                              hipStream_t stream) {
  const float* x   = (const float*)d_in[0];
  const void*  ei  = d_in[1];
  const float* eps = (const float*)d_in[2];
  const float* W1  = (const float*)d_in[3];
  const float* b1  = (const float*)d_in[4];
  const float* W2  = (const float*)d_in[5];
  const float* b2  = (const float*)d_in[6];
  float* out = (float*)d_out;

  const int n_nodes = in_sizes[0] / D;
  const int n_edges = in_sizes[1] / 2;

  // Pick the largest shard count the workspace supports.
  // ws layout (ints): C[S*n_nodes] | tsum[SCAN_CHUNKS] | sorted[E]
  int S = 0;
  for (int cand = 8; cand >= 1; cand >>= 1) {
    const size_t need =
        ((size_t)cand * n_nodes + SCAN_CHUNKS + (size_t)n_edges) * 4;
    if (ws_size >= need) { S = cand; break; }
  }

  if (S > 0) {
    int* C      = (int*)d_ws;
    int* tsum   = C + (size_t)S * n_nodes;
    int* sorted = tsum + SCAN_CHUNKS;
    const int total = S * n_nodes;

    (void)hipMemsetAsync(C, 0, (size_t)total * 4, stream);

    gin_hist_sharded<<<EDGE_GRID, EDGE_BLOCK, 0, stream>>>(ei, C, n_edges,
                                                           n_nodes, S);

    const int chunk = (total + SCAN_CHUNKS - 1) / SCAN_CHUNKS;
    gin_scan_a<<<SCAN_CHUNKS / 256, 256, 0, stream>>>(C, tsum, total, chunk);
    gin_scan_b<<<1, 1024, 0, stream>>>(tsum);
    gin_scan_c<<<SCAN_CHUNKS / 256, 256, 0, stream>>>(C, tsum, total, chunk);

    gin_place_sharded<<<EDGE_GRID, EDGE_BLOCK, 0, stream>>>(ei, C, sorted,
                                                            n_edges, n_nodes,
                                                            S);

    const int gather_blocks = (n_nodes * 64 + 255) / 256;
    switch (S) {
      case 8:
        gin_gather_sharded<8><<<gather_blocks, 256, 0, stream>>>(
            x, C, sorted, out, n_nodes);
        break;
      case 4:
        gin_gather_sharded<4><<<gather_blocks, 256, 0, stream>>>(
            x, C, sorted, out, n_nodes);
        break;
      case 2:
        gin_gather_sharded<2><<<gather_blocks, 256, 0, stream>>>(
            x, C, sorted, out, n_nodes);
        break;
      default:
        gin_gather_sharded<1><<<gather_blocks, 256, 0, stream>>>(
            x, C, sorted, out, n_nodes);
        break;
    }
  } else {
    (void)hipMemsetAsync(out, 0, (size_t)n_nodes * D * sizeof(float), stream);
    gin_scatter_atomic<<<4096, 256, 0, stream>>>(x, ei, out, n_edges);
  }

  const int mlp_blocks = (n_nodes + 255) / 256;
  gin_mlp_kernel<<<mlp_blocks, 256, 0, stream>>>(x, out, eps, W1, b1, W2, b2,
                                                 out, n_nodes);
}